// Round 1
// baseline (209.089 us; speedup 1.0000x reference)
//
#include <hip/hip_runtime.h>
#include <math.h>

#define N_NODES 50000
#define N_EDGES 800000
#define DOUT 64
#define NHEAD 8
#define RP1 9            // num_relations + 1 (self-loop relation id = 8)
#define NEG_SLOPE 0.2f
#define EPS_F 1e-10f
#define M_TOT (N_EDGES + N_NODES)   // 850000 edges incl. self-loops
#define NW (RP1 * DOUT * DOUT)      // 36,864 W elements
#define RNG (N_NODES / 8)           // 6250 nodes per XCD-range
#define EPB 2048                    // edges per chunk
#define CHUNKS ((M_TOT + EPB - 1) / EPB)   // 416
#define BUCK 48                     // fixed bucket slots/node; P(deg+1 > 48) ~ 1e-26
#define MBLK ((M_TOT + 255) / 256)  // kprep2 blocks
#define FILLB (CHUNKS * 8)          // 3328 fill-role blocks (multiple of 8!)
#define K1B ((N_NODES + 63) / 64)   // 782 k1-role blocks

typedef __attribute__((ext_vector_type(8))) short bf16x8;
typedef __attribute__((ext_vector_type(4))) float f32x4;

__device__ __forceinline__ unsigned short f2bf(float f) {
    unsigned int u = __float_as_uint(f);
    unsigned int r = (u + 0x7FFFu + ((u >> 16) & 1u)) >> 16;   // RNE
    return (unsigned short)r;
}
__device__ __forceinline__ float bf2f(unsigned short s) {
    return __uint_as_float(((unsigned int)s) << 16);
}

// ===========================================================================
// kprep2 (R16): coalesced per-edge meta  meta_by_m[m] = {ni|rel<<16, ew}
// + W f32->bf16 + cursor zeroing (memset dispatch folded in).
// ===========================================================================
__global__ __launch_bounds__(256) void kprep2(const int* __restrict__ node_in,
                                              const int* __restrict__ relation,
                                              const float* __restrict__ edge_weight,
                                              const float* __restrict__ W,
                                              int2* __restrict__ meta_by_m,
                                              unsigned short* __restrict__ Wb,
                                              int* __restrict__ cursor) {
    int m = blockIdx.x * 256 + threadIdx.x;
    if (m < NW / 4) {
        int i = m * 4;
        float4 v = *(const float4*)(W + i);
        ushort4 o; o.x = f2bf(v.x); o.y = f2bf(v.y); o.z = f2bf(v.z); o.w = f2bf(v.w);
        *(ushort4*)(Wb + i) = o;
    }
    if (m < N_NODES) cursor[m] = 0;               // replaces hipMemsetAsync
    if (m >= M_TOT) return;
    int ni, rl; float ew;
    if (m < N_EDGES) {
        ni = node_in[m]; rl = relation[m]; ew = edge_weight[m];
    } else {
        ni = m - N_EDGES; rl = RP1 - 1; ew = 1.0f;
    }
    int2 v; v.x = ni | (rl << 16); v.y = __float_as_int(ew);
    meta_by_m[m] = v;                               // coalesced full-line write
}

// ===========================================================================
// kbig (R16): kfillb and k1_mfma are INDEPENDENT (fill consumes edge meta,
// k1 consumes x/W) but were serialized on one stream. Graph capture forbids
// multi-stream fork/join, so concurrency = single launch, block-role split:
//   blocks [0, FILLB)        : bucket fill  (FILLB % 8 == 0 keeps r=blk&7
//                              XCD round-robin identical to standalone kfillb)
//   blocks [FILLB, FILLB+K1B): MFMA transform (bx = blockIdx.x - FILLB)
// The atomic-latency-bound fill overlaps with the HBM-BW-bound transform.
// Fill delta vs R15: meta_by_m loaded only INSIDE the range predicate
// (~1/8 lanes), trimming the 8x-redundant meta TCC traffic.
// ===========================================================================
__global__ __launch_bounds__(256) void kbig(const float* __restrict__ x,
                                            const unsigned short* __restrict__ Wb,
                                            unsigned short* __restrict__ hiddenb,
                                            const int* __restrict__ node_out,
                                            const int2* __restrict__ meta_by_m,
                                            int* __restrict__ cursor,
                                            int2* __restrict__ bucket) {
    const int t = threadIdx.x;

    if (blockIdx.x < FILLB) {
        // ---------------- fill role ----------------
        const int r = blockIdx.x & 7;
        const int chunk = blockIdx.x >> 3;
        const int lo = r * RNG;
        const int hi = lo + RNG;
        int m = chunk * EPB + t;
#pragma unroll
        for (int it = 0; it < EPB / 256; it++, m += 256) {
            if (m < M_TOT) {
                int no = (m < N_EDGES) ? node_out[m] : (m - N_EDGES);
                if (no >= lo && no < hi) {
                    int2 v = meta_by_m[m];          // only in-range lanes fetch
                    int pos = atomicAdd(&cursor[no], 1);
                    if (pos < BUCK) bucket[(size_t)no * BUCK + pos] = v;
                }
            }
        }
        return;
    }

    // ---------------- k1 (MFMA) role ----------------
    __shared__ float xs[64 * 68];
    __shared__ unsigned short st[4 * 16 * 72];
    const int bx = blockIdx.x - FILLB;
    const int wv = t >> 6, lane = t & 63;
    const int quad = lane >> 4, l16 = lane & 15;
    const int base = bx * 64 + wv * 16;

    for (int q = t; q < 64 * 64 / 4; q += 256) {
        int flat = q * 4;
        int row = flat >> 6;
        int col = flat & 63;
        int n = bx * 64 + row;
        float4 v = make_float4(0.f, 0.f, 0.f, 0.f);
        if (n < N_NODES) v = *(const float4*)(x + (size_t)n * 64 + col);
        float* p = &xs[row * 68 + col];
        p[0] = v.x; p[1] = v.y; p[2] = v.z; p[3] = v.w;
    }
    __syncthreads();

    int arowl = wv * 16 + l16;
    bf16x8 a0, a1;
#pragma unroll
    for (int j = 0; j < 8; j++) {
        a0[j] = (short)f2bf(xs[arowl * 68 + quad * 8 + j]);
        a1[j] = (short)f2bf(xs[arowl * 68 + quad * 8 + 32 + j]);
    }

    unsigned short* sw = &st[wv * 16 * 72];

    for (int r = 0; r < RP1; r++) {
        const unsigned short* Wr = Wb + r * 4096;
        f32x4 acc[4];
#pragma unroll
        for (int dt = 0; dt < 4; dt++) {
            const bf16x8 b0 = *(const bf16x8*)(Wr + (dt * 16 + l16) * 64 + quad * 8);
            const bf16x8 b1 = *(const bf16x8*)(Wr + (dt * 16 + l16) * 64 + quad * 8 + 32);
            f32x4 c = {0.f, 0.f, 0.f, 0.f};
            c = __builtin_amdgcn_mfma_f32_16x16x32_bf16(a0, b0, c, 0, 0, 0);
            c = __builtin_amdgcn_mfma_f32_16x16x32_bf16(a1, b1, c, 0, 0, 0);
            acc[dt] = c;
        }
#pragma unroll
        for (int dt = 0; dt < 4; dt++) {
#pragma unroll
            for (int v = 0; v < 4; v++) {
                sw[(quad * 4 + v) * 72 + dt * 16 + l16] = f2bf(acc[dt][v]);
            }
        }
        __threadfence_block();
#pragma unroll
        for (int q = 0; q < 2; q++) {
            int cid = q * 64 + lane;
            int row = cid >> 3;
            int ch = cid & 7;
            int n = base + row;
            if (n < N_NODES) {
                bf16x8 v = *(const bf16x8*)(sw + row * 72 + ch * 8);
                *(bf16x8*)(hiddenb + ((size_t)r * N_NODES + n) * 64 + ch * 8) = v;
            }
        }
        __threadfence_block();
    }
}

// ===========================================================================
// K3 (fused, unchanged from R15): wave = TWO nodes, chunk = 32 slots/node.
// ===========================================================================
__global__ __launch_bounds__(256) void k3_fused2(const unsigned short* __restrict__ hiddenb,
                                                 const float* __restrict__ query,
                                                 const int2* __restrict__ bucket,
                                                 const int* __restrict__ deg,
                                                 float* __restrict__ out) {
    __shared__ float qe[RP1 * 64];
    __shared__ float qo[RP1 * 64];
    __shared__ int2  meta[4][64];
    __shared__ float bho[4][2][72];

    const int t = threadIdx.x;
    for (int q = t; q < RP1 * 64; q += 256) {
        int j = q & 7, rh = q >> 3;
        qe[q] = query[rh * 16 + 2 * j];
        qo[q] = query[rh * 16 + 2 * j + 1];
    }
    __syncthreads();

    const int wv = t >> 6, lane = t & 63;
    const int pairi = blockIdx.x * 4 + wv;
    const int nA = pairi * 2, nB = nA + 1;
    const int e_lo = lane >> 3, h = lane & 7;

    {
        const int prel = lane >> 3, ph = lane & 7;
        bf16x8 ra = *(const bf16x8*)(hiddenb + ((size_t)(prel * N_NODES + nA)) * 64 + ph * 8);
        bf16x8 rb = *(const bf16x8*)(hiddenb + ((size_t)(prel * N_NODES + nB)) * 64 + ph * 8);
        bf16x8 r8 = ra;
        if (lane < 16) {
            int n8 = (lane < 8) ? nA : nB;
            r8 = *(const bf16x8*)(hiddenb + ((size_t)(8 * N_NODES + n8)) * 64 + (lane & 7) * 8);
        }
        const float* qop = &qo[(prel * 8 + ph) * 8];
        float da = 0.f, db = 0.f;
#pragma unroll
        for (int j = 0; j < 8; j++) {
            da += qop[j] * bf2f((unsigned short)ra[j]);
            db += qop[j] * bf2f((unsigned short)rb[j]);
        }
        bho[wv][0][prel * 8 + ph] = da;
        bho[wv][1][prel * 8 + ph] = db;
        if (lane < 16) {
            const float* q8p = &qo[(64 + (lane & 7)) * 8];
            float d8 = 0.f;
#pragma unroll
            for (int j = 0; j < 8; j++) d8 += q8p[j] * bf2f((unsigned short)r8[j]);
            bho[wv][(lane < 8) ? 0 : 1][64 + (lane & 7)] = d8;
        }
    }
    __threadfence_block();

    const int degAi = deg[nA], degBi = deg[nB];
    const int begA = nA * BUCK, endA = begA + min(degAi, BUCK);
    const int begB = nB * BUCK, endB = begB + min(degBi, BUCK);
    const float degA = (float)degAi, degB = (float)degBi;

    float accA[8] = {0.f, 0.f, 0.f, 0.f, 0.f, 0.f, 0.f, 0.f};
    float accB[8] = {0.f, 0.f, 0.f, 0.f, 0.f, 0.f, 0.f, 0.f};
    float spA = 0.f, spB = 0.f;
    int cbA = begA, cbB = begB;

    while (cbA < endA || cbB < endB) {
        const int cA = min(32, endA - cbA);
        const int cB = min(32, endB - cbB);

        int2 mt; mt.x = nA | ((RP1 - 1) << 16); mt.y = 0;   // dummy: ew=0
        if (lane < 32) {
            if (lane < cA) mt = bucket[cbA + lane];
        } else {
            int l2 = lane - 32;
            if (l2 < cB) mt = bucket[cbB + l2];
        }
        meta[wv][lane] = mt;
        __threadfence_block();

        const int npA = (cA + 7) >> 3, npB = (cB + 7) >> 3;

        bf16x8 rA[4], rB[4];
        int relA[4], relB[4]; float ewA[4], ewB[4];
#pragma unroll
        for (int p = 0; p < 4; p++) {
            if (p < npA) {
                int2 m2 = meta[wv][p * 8 + e_lo];
                int ni = m2.x & 0xffff, rl = m2.x >> 16;
                relA[p] = rl; ewA[p] = __int_as_float(m2.y);
                rA[p] = *(const bf16x8*)(hiddenb + ((size_t)(rl * N_NODES + ni)) * 64 + h * 8);
            }
            if (p < npB) {
                int2 m2 = meta[wv][32 + p * 8 + e_lo];
                int ni = m2.x & 0xffff, rl = m2.x >> 16;
                relB[p] = rl; ewB[p] = __int_as_float(m2.y);
                rB[p] = *(const bf16x8*)(hiddenb + ((size_t)(rl * N_NODES + ni)) * 64 + h * 8);
            }
        }

#pragma unroll
        for (int p = 0; p < 4; p++) {
            if (p < npA) {
                const float* qp = &qe[(relA[p] * 8 + h) * 8];
                float hif[8];
#pragma unroll
                for (int j = 0; j < 8; j++) hif[j] = bf2f((unsigned short)rA[p][j]);
                float wp = bho[wv][0][relA[p] * 8 + h];
#pragma unroll
                for (int j = 0; j < 8; j++) wp += qp[j] * hif[j];
                wp = (wp > 0.f) ? wp : NEG_SLOPE * wp;
                float pa = __expf(wp) * ewA[p];
#pragma unroll
                for (int j = 0; j < 8; j++) accA[j] += pa * hif[j];
                spA += pa;
            }
            if (p < npB) {
                const float* qp = &qe[(relB[p] * 8 + h) * 8];
                float hif[8];
#pragma unroll
                for (int j = 0; j < 8; j++) hif[j] = bf2f((unsigned short)rB[p][j]);
                float wp = bho[wv][1][relB[p] * 8 + h];
#pragma unroll
                for (int j = 0; j < 8; j++) wp += qp[j] * hif[j];
                wp = (wp > 0.f) ? wp : NEG_SLOPE * wp;
                float pa = __expf(wp) * ewB[p];
#pragma unroll
                for (int j = 0; j < 8; j++) accB[j] += pa * hif[j];
                spB += pa;
            }
        }

        cbA += cA; cbB += cB;
    }

#pragma unroll
    for (int j = 0; j < 8; j++) {
        accA[j] += __shfl_xor(accA[j], 8);
        accA[j] += __shfl_xor(accA[j], 16);
        accA[j] += __shfl_xor(accA[j], 32);
        accB[j] += __shfl_xor(accB[j], 8);
        accB[j] += __shfl_xor(accB[j], 16);
        accB[j] += __shfl_xor(accB[j], 32);
    }
    spA += __shfl_xor(spA, 8); spA += __shfl_xor(spA, 16); spA += __shfl_xor(spA, 32);
    spB += __shfl_xor(spB, 8); spB += __shfl_xor(spB, 16); spB += __shfl_xor(spB, 32);

    if (lane < 8) {
        const float s = 1.f / ((spA / degA + EPS_F) * degA);
        float4 o0, o1;
        o0.x = fmaxf(accA[0] * s, 0.f); o0.y = fmaxf(accA[1] * s, 0.f);
        o0.z = fmaxf(accA[2] * s, 0.f); o0.w = fmaxf(accA[3] * s, 0.f);
        o1.x = fmaxf(accA[4] * s, 0.f); o1.y = fmaxf(accA[5] * s, 0.f);
        o1.z = fmaxf(accA[6] * s, 0.f); o1.w = fmaxf(accA[7] * s, 0.f);
        float* op = out + (size_t)nA * 64 + lane * 8;
        *(float4*)(op) = o0; *(float4*)(op + 4) = o1;
    } else if (lane < 16) {
        const float s = 1.f / ((spB / degB + EPS_F) * degB);
        float4 o0, o1;
        o0.x = fmaxf(accB[0] * s, 0.f); o0.y = fmaxf(accB[1] * s, 0.f);
        o0.z = fmaxf(accB[2] * s, 0.f); o0.w = fmaxf(accB[3] * s, 0.f);
        o1.x = fmaxf(accB[4] * s, 0.f); o1.y = fmaxf(accB[5] * s, 0.f);
        o1.z = fmaxf(accB[6] * s, 0.f); o1.w = fmaxf(accB[7] * s, 0.f);
        float* op = out + (size_t)nB * 64 + (lane - 8) * 8;
        *(float4*)(op) = o0; *(float4*)(op + 4) = o1;
    }
}

extern "C" void kernel_launch(void* const* d_in, const int* in_sizes, int n_in,
                              void* d_out, int out_size, void* d_ws, size_t ws_size,
                              hipStream_t stream) {
    const float* x        = (const float*)d_in[0];
    const float* W_tau    = (const float*)d_in[1];
    const float* query    = (const float*)d_in[2];
    const int*   node_in  = (const int*)d_in[3];
    const int*   node_out = (const int*)d_in[4];
    const int*   relation = (const int*)d_in[5];
    const float* edge_w   = (const float*)d_in[6];
    float* out = (float*)d_out;

    char* ws = (char*)d_ws;
    unsigned short* hiddenb   = (unsigned short*)(ws);                // 57,600,000
    unsigned short* Wb        = (unsigned short*)(ws + 57600000);     //     73,728
    int2*           meta_by_m = (int2*)(ws + 57673728);               //  6,800,000
    int2*           bucket    = (int2*)(ws + 64473728);               // 19,200,000
    int*            cursor    = (int*)(ws + 83673728);                //    200,000

    // per-edge meta + W conversion + cursor zeroing (coalesced streaming)
    kprep2<<<MBLK, 256, 0, stream>>>(node_in, relation, edge_w, W_tau,
                                     meta_by_m, Wb, cursor);

    // merged: bucket fill (blocks 0..FILLB) CONCURRENT with MFMA transform
    kbig<<<FILLB + K1B, 256, 0, stream>>>(x, Wb, hiddenb, node_out, meta_by_m,
                                          cursor, bucket);

    // fused logits + aggregation + relu (2 nodes per wave)
    k3_fused2<<<(N_NODES / 2 + 3) / 4, 256, 0, stream>>>(hiddenb, query, bucket,
                                                         cursor, out);
}

// Round 2
// 178.161 us; speedup vs baseline: 1.1736x; 1.1736x over previous
//
#include <hip/hip_runtime.h>
#include <math.h>

#define N_NODES 50000
#define N_EDGES 800000
#define DOUT 64
#define NHEAD 8
#define RP1 9            // num_relations + 1 (self-loop relation id = 8)
#define NEG_SLOPE 0.2f
#define EPS_F 1e-10f
#define M_TOT (N_EDGES + N_NODES)   // 850000 edges incl. self-loops
#define NW (RP1 * DOUT * DOUT)      // 36,864 W elements
#define RNG (N_NODES / 8)           // 6250 nodes per XCD-range
#define EPB 2048                    // edges per chunk
#define CHUNKS ((M_TOT + EPB - 1) / EPB)   // 416
#define BUCK 48                     // fixed bucket slots/node; P(deg+1 > 48) ~ 1e-26
#define MBLK ((M_TOT + 255) / 256)  // kprep2 blocks
#define FILLB (CHUNKS * 8)          // 3328 fill-role blocks
#define K1B ((N_NODES + 63) / 64)   // 782 k1-role blocks
#define K1PAD 784                   // k1 role padded to multiple of 8 so the
                                    // fill role's f&7 -> XCD map stays bijective

typedef __attribute__((ext_vector_type(8))) short bf16x8;
typedef __attribute__((ext_vector_type(4))) float f32x4;

__device__ __forceinline__ unsigned short f2bf(float f) {
    unsigned int u = __float_as_uint(f);
    unsigned int r = (u + 0x7FFFu + ((u >> 16) & 1u)) >> 16;   // RNE
    return (unsigned short)r;
}
__device__ __forceinline__ float bf2f(unsigned short s) {
    return __uint_as_float(((unsigned int)s) << 16);
}

// ===========================================================================
// kprep2: coalesced per-edge meta  meta_by_m[m] = {ni|rel<<16, ew}
// + W f32->bf16 + cursor zeroing (memset dispatch folded in).
// ===========================================================================
__global__ __launch_bounds__(256) void kprep2(const int* __restrict__ node_in,
                                              const int* __restrict__ relation,
                                              const float* __restrict__ edge_weight,
                                              const float* __restrict__ W,
                                              int2* __restrict__ meta_by_m,
                                              unsigned short* __restrict__ Wb,
                                              int* __restrict__ cursor) {
    int m = blockIdx.x * 256 + threadIdx.x;
    if (m < NW / 4) {
        int i = m * 4;
        float4 v = *(const float4*)(W + i);
        ushort4 o; o.x = f2bf(v.x); o.y = f2bf(v.y); o.z = f2bf(v.z); o.w = f2bf(v.w);
        *(ushort4*)(Wb + i) = o;
    }
    if (m < N_NODES) cursor[m] = 0;               // replaces hipMemsetAsync
    if (m >= M_TOT) return;
    int ni, rl; float ew;
    if (m < N_EDGES) {
        ni = node_in[m]; rl = relation[m]; ew = edge_weight[m];
    } else {
        ni = m - N_EDGES; rl = RP1 - 1; ew = 1.0f;
    }
    int2 v; v.x = ni | (rl << 16); v.y = __float_as_int(ew);
    meta_by_m[m] = v;                               // coalesced full-line write
}

// ===========================================================================
// kbig (R17): block-role merge with the LONG role FIRST.
//   blocks [0, K1PAD)           : MFMA transform (782 working + 2 idle pad)
//   blocks [K1PAD, K1PAD+FILLB) : bucket fill, f = blockIdx - K1PAD
// R16 post-mortem: fill-first ordering gave zero overlap (short fill blocks
// drained before k1 launched) and the predicated meta load was latency-bound
// (41 MB fetch but SLOWER: scattered 8B loads, no MLP). R17 fixes both:
// k1 blocks are resident first so fill blocks stream in behind them, and the
// fill role restores the R15 coalesced unconditional chunk read.
// ===========================================================================
__global__ __launch_bounds__(256) void kbig(const float* __restrict__ x,
                                            const unsigned short* __restrict__ Wb,
                                            unsigned short* __restrict__ hiddenb,
                                            const int* __restrict__ node_out,
                                            const int2* __restrict__ meta_by_m,
                                            int* __restrict__ cursor,
                                            int2* __restrict__ bucket) {
    const int t = threadIdx.x;

    if (blockIdx.x >= K1PAD) {
        // ---------------- fill role (R15 body, coalesced meta) ----------------
        const int f = blockIdx.x - K1PAD;
        const int r = f & 7;
        const int chunk = f >> 3;
        const int lo = r * RNG;
        const int hi = lo + RNG;
        int m = chunk * EPB + t;
#pragma unroll
        for (int it = 0; it < EPB / 256; it++, m += 256) {
            if (m < M_TOT) {
                int2 v = meta_by_m[m];              // coalesced (full chunk)
                int no = (m < N_EDGES) ? node_out[m] : (m - N_EDGES);
                if (no >= lo && no < hi) {
                    int pos = atomicAdd(&cursor[no], 1);
                    if (pos < BUCK) bucket[(size_t)no * BUCK + pos] = v;
                }
            }
        }
        return;
    }

    // ---------------- k1 (MFMA) role ----------------
    const int bx = blockIdx.x;
    if (bx >= K1B) return;                          // pad blocks
    __shared__ float xs[64 * 68];
    __shared__ unsigned short st[4 * 16 * 72];
    const int wv = t >> 6, lane = t & 63;
    const int quad = lane >> 4, l16 = lane & 15;
    const int base = bx * 64 + wv * 16;

    for (int q = t; q < 64 * 64 / 4; q += 256) {
        int flat = q * 4;
        int row = flat >> 6;
        int col = flat & 63;
        int n = bx * 64 + row;
        float4 v = make_float4(0.f, 0.f, 0.f, 0.f);
        if (n < N_NODES) v = *(const float4*)(x + (size_t)n * 64 + col);
        float* p = &xs[row * 68 + col];
        p[0] = v.x; p[1] = v.y; p[2] = v.z; p[3] = v.w;
    }
    __syncthreads();

    int arowl = wv * 16 + l16;
    bf16x8 a0, a1;
#pragma unroll
    for (int j = 0; j < 8; j++) {
        a0[j] = (short)f2bf(xs[arowl * 68 + quad * 8 + j]);
        a1[j] = (short)f2bf(xs[arowl * 68 + quad * 8 + 32 + j]);
    }

    unsigned short* sw = &st[wv * 16 * 72];

    for (int r = 0; r < RP1; r++) {
        const unsigned short* Wr = Wb + r * 4096;
        f32x4 acc[4];
#pragma unroll
        for (int dt = 0; dt < 4; dt++) {
            const bf16x8 b0 = *(const bf16x8*)(Wr + (dt * 16 + l16) * 64 + quad * 8);
            const bf16x8 b1 = *(const bf16x8*)(Wr + (dt * 16 + l16) * 64 + quad * 8 + 32);
            f32x4 c = {0.f, 0.f, 0.f, 0.f};
            c = __builtin_amdgcn_mfma_f32_16x16x32_bf16(a0, b0, c, 0, 0, 0);
            c = __builtin_amdgcn_mfma_f32_16x16x32_bf16(a1, b1, c, 0, 0, 0);
            acc[dt] = c;
        }
#pragma unroll
        for (int dt = 0; dt < 4; dt++) {
#pragma unroll
            for (int v = 0; v < 4; v++) {
                sw[(quad * 4 + v) * 72 + dt * 16 + l16] = f2bf(acc[dt][v]);
            }
        }
        __threadfence_block();
#pragma unroll
        for (int q = 0; q < 2; q++) {
            int cid = q * 64 + lane;
            int row = cid >> 3;
            int ch = cid & 7;
            int n = base + row;
            if (n < N_NODES) {
                bf16x8 v = *(const bf16x8*)(sw + row * 72 + ch * 8);
                *(bf16x8*)(hiddenb + ((size_t)r * N_NODES + n) * 64 + ch * 8) = v;
            }
        }
        __threadfence_block();
    }
}

// ===========================================================================
// K3 (fused, unchanged): wave = TWO nodes, chunk = 32 slots/node.
// ===========================================================================
__global__ __launch_bounds__(256) void k3_fused2(const unsigned short* __restrict__ hiddenb,
                                                 const float* __restrict__ query,
                                                 const int2* __restrict__ bucket,
                                                 const int* __restrict__ deg,
                                                 float* __restrict__ out) {
    __shared__ float qe[RP1 * 64];
    __shared__ float qo[RP1 * 64];
    __shared__ int2  meta[4][64];
    __shared__ float bho[4][2][72];

    const int t = threadIdx.x;
    for (int q = t; q < RP1 * 64; q += 256) {
        int j = q & 7, rh = q >> 3;
        qe[q] = query[rh * 16 + 2 * j];
        qo[q] = query[rh * 16 + 2 * j + 1];
    }
    __syncthreads();

    const int wv = t >> 6, lane = t & 63;
    const int pairi = blockIdx.x * 4 + wv;
    const int nA = pairi * 2, nB = nA + 1;
    const int e_lo = lane >> 3, h = lane & 7;

    {
        const int prel = lane >> 3, ph = lane & 7;
        bf16x8 ra = *(const bf16x8*)(hiddenb + ((size_t)(prel * N_NODES + nA)) * 64 + ph * 8);
        bf16x8 rb = *(const bf16x8*)(hiddenb + ((size_t)(prel * N_NODES + nB)) * 64 + ph * 8);
        bf16x8 r8 = ra;
        if (lane < 16) {
            int n8 = (lane < 8) ? nA : nB;
            r8 = *(const bf16x8*)(hiddenb + ((size_t)(8 * N_NODES + n8)) * 64 + (lane & 7) * 8);
        }
        const float* qop = &qo[(prel * 8 + ph) * 8];
        float da = 0.f, db = 0.f;
#pragma unroll
        for (int j = 0; j < 8; j++) {
            da += qop[j] * bf2f((unsigned short)ra[j]);
            db += qop[j] * bf2f((unsigned short)rb[j]);
        }
        bho[wv][0][prel * 8 + ph] = da;
        bho[wv][1][prel * 8 + ph] = db;
        if (lane < 16) {
            const float* q8p = &qo[(64 + (lane & 7)) * 8];
            float d8 = 0.f;
#pragma unroll
            for (int j = 0; j < 8; j++) d8 += q8p[j] * bf2f((unsigned short)r8[j]);
            bho[wv][(lane < 8) ? 0 : 1][64 + (lane & 7)] = d8;
        }
    }
    __threadfence_block();

    const int degAi = deg[nA], degBi = deg[nB];
    const int begA = nA * BUCK, endA = begA + min(degAi, BUCK);
    const int begB = nB * BUCK, endB = begB + min(degBi, BUCK);
    const float degA = (float)degAi, degB = (float)degBi;

    float accA[8] = {0.f, 0.f, 0.f, 0.f, 0.f, 0.f, 0.f, 0.f};
    float accB[8] = {0.f, 0.f, 0.f, 0.f, 0.f, 0.f, 0.f, 0.f};
    float spA = 0.f, spB = 0.f;
    int cbA = begA, cbB = begB;

    while (cbA < endA || cbB < endB) {
        const int cA = min(32, endA - cbA);
        const int cB = min(32, endB - cbB);

        int2 mt; mt.x = nA | ((RP1 - 1) << 16); mt.y = 0;   // dummy: ew=0
        if (lane < 32) {
            if (lane < cA) mt = bucket[cbA + lane];
        } else {
            int l2 = lane - 32;
            if (l2 < cB) mt = bucket[cbB + l2];
        }
        meta[wv][lane] = mt;
        __threadfence_block();

        const int npA = (cA + 7) >> 3, npB = (cB + 7) >> 3;

        bf16x8 rA[4], rB[4];
        int relA[4], relB[4]; float ewA[4], ewB[4];
#pragma unroll
        for (int p = 0; p < 4; p++) {
            if (p < npA) {
                int2 m2 = meta[wv][p * 8 + e_lo];
                int ni = m2.x & 0xffff, rl = m2.x >> 16;
                relA[p] = rl; ewA[p] = __int_as_float(m2.y);
                rA[p] = *(const bf16x8*)(hiddenb + ((size_t)(rl * N_NODES + ni)) * 64 + h * 8);
            }
            if (p < npB) {
                int2 m2 = meta[wv][32 + p * 8 + e_lo];
                int ni = m2.x & 0xffff, rl = m2.x >> 16;
                relB[p] = rl; ewB[p] = __int_as_float(m2.y);
                rB[p] = *(const bf16x8*)(hiddenb + ((size_t)(rl * N_NODES + ni)) * 64 + h * 8);
            }
        }

#pragma unroll
        for (int p = 0; p < 4; p++) {
            if (p < npA) {
                const float* qp = &qe[(relA[p] * 8 + h) * 8];
                float hif[8];
#pragma unroll
                for (int j = 0; j < 8; j++) hif[j] = bf2f((unsigned short)rA[p][j]);
                float wp = bho[wv][0][relA[p] * 8 + h];
#pragma unroll
                for (int j = 0; j < 8; j++) wp += qp[j] * hif[j];
                wp = (wp > 0.f) ? wp : NEG_SLOPE * wp;
                float pa = __expf(wp) * ewA[p];
#pragma unroll
                for (int j = 0; j < 8; j++) accA[j] += pa * hif[j];
                spA += pa;
            }
            if (p < npB) {
                const float* qp = &qe[(relB[p] * 8 + h) * 8];
                float hif[8];
#pragma unroll
                for (int j = 0; j < 8; j++) hif[j] = bf2f((unsigned short)rB[p][j]);
                float wp = bho[wv][1][relB[p] * 8 + h];
#pragma unroll
                for (int j = 0; j < 8; j++) wp += qp[j] * hif[j];
                wp = (wp > 0.f) ? wp : NEG_SLOPE * wp;
                float pa = __expf(wp) * ewB[p];
#pragma unroll
                for (int j = 0; j < 8; j++) accB[j] += pa * hif[j];
                spB += pa;
            }
        }

        cbA += cA; cbB += cB;
    }

#pragma unroll
    for (int j = 0; j < 8; j++) {
        accA[j] += __shfl_xor(accA[j], 8);
        accA[j] += __shfl_xor(accA[j], 16);
        accA[j] += __shfl_xor(accA[j], 32);
        accB[j] += __shfl_xor(accB[j], 8);
        accB[j] += __shfl_xor(accB[j], 16);
        accB[j] += __shfl_xor(accB[j], 32);
    }
    spA += __shfl_xor(spA, 8); spA += __shfl_xor(spA, 16); spA += __shfl_xor(spA, 32);
    spB += __shfl_xor(spB, 8); spB += __shfl_xor(spB, 16); spB += __shfl_xor(spB, 32);

    if (lane < 8) {
        const float s = 1.f / ((spA / degA + EPS_F) * degA);
        float4 o0, o1;
        o0.x = fmaxf(accA[0] * s, 0.f); o0.y = fmaxf(accA[1] * s, 0.f);
        o0.z = fmaxf(accA[2] * s, 0.f); o0.w = fmaxf(accA[3] * s, 0.f);
        o1.x = fmaxf(accA[4] * s, 0.f); o1.y = fmaxf(accA[5] * s, 0.f);
        o1.z = fmaxf(accA[6] * s, 0.f); o1.w = fmaxf(accA[7] * s, 0.f);
        float* op = out + (size_t)nA * 64 + lane * 8;
        *(float4*)(op) = o0; *(float4*)(op + 4) = o1;
    } else if (lane < 16) {
        const float s = 1.f / ((spB / degB + EPS_F) * degB);
        float4 o0, o1;
        o0.x = fmaxf(accB[0] * s, 0.f); o0.y = fmaxf(accB[1] * s, 0.f);
        o0.z = fmaxf(accB[2] * s, 0.f); o0.w = fmaxf(accB[3] * s, 0.f);
        o1.x = fmaxf(accB[4] * s, 0.f); o1.y = fmaxf(accB[5] * s, 0.f);
        o1.z = fmaxf(accB[6] * s, 0.f); o1.w = fmaxf(accB[7] * s, 0.f);
        float* op = out + (size_t)nB * 64 + (lane - 8) * 8;
        *(float4*)(op) = o0; *(float4*)(op + 4) = o1;
    }
}

extern "C" void kernel_launch(void* const* d_in, const int* in_sizes, int n_in,
                              void* d_out, int out_size, void* d_ws, size_t ws_size,
                              hipStream_t stream) {
    const float* x        = (const float*)d_in[0];
    const float* W_tau    = (const float*)d_in[1];
    const float* query    = (const float*)d_in[2];
    const int*   node_in  = (const int*)d_in[3];
    const int*   node_out = (const int*)d_in[4];
    const int*   relation = (const int*)d_in[5];
    const float* edge_w   = (const float*)d_in[6];
    float* out = (float*)d_out;

    char* ws = (char*)d_ws;
    unsigned short* hiddenb   = (unsigned short*)(ws);                // 57,600,000
    unsigned short* Wb        = (unsigned short*)(ws + 57600000);     //     73,728
    int2*           meta_by_m = (int2*)(ws + 57673728);               //  6,800,000
    int2*           bucket    = (int2*)(ws + 64473728);               // 19,200,000
    int*            cursor    = (int*)(ws + 83673728);                //    200,000

    // per-edge meta + W conversion + cursor zeroing (coalesced streaming)
    kprep2<<<MBLK, 256, 0, stream>>>(node_in, relation, edge_w, W_tau,
                                     meta_by_m, Wb, cursor);

    // merged: MFMA transform (blocks 0..K1PAD, resident FIRST) overlapped
    // with bucket fill (blocks K1PAD..K1PAD+FILLB streaming in behind)
    kbig<<<K1PAD + FILLB, 256, 0, stream>>>(x, Wb, hiddenb, node_out, meta_by_m,
                                            cursor, bucket);

    // fused logits + aggregation + relu (2 nodes per wave)
    k3_fused2<<<(N_NODES / 2 + 3) / 4, 256, 0, stream>>>(hiddenb, query, bucket,
                                                         cursor, out);
}

// Round 3
// 169.243 us; speedup vs baseline: 1.2354x; 1.0527x over previous
//
#include <hip/hip_runtime.h>
#include <math.h>

#define N_NODES 50000
#define N_EDGES 800000
#define DOUT 64
#define NHEAD 8
#define RP1 9            // num_relations + 1 (self-loop relation id = 8)
#define NEG_SLOPE 0.2f
#define EPS_F 1e-10f
#define M_TOT (N_EDGES + N_NODES)   // 850000 edges incl. self-loops
#define NW (RP1 * DOUT * DOUT)      // 36,864 W elements
#define RNG (N_NODES / 8)           // 6250 nodes per XCD-range
#define EPB 2048                    // edges per chunk
#define CHUNKS ((M_TOT + EPB - 1) / EPB)   // 416
#define BUCK 48                     // fixed bucket slots/node; P(deg+1 > 48) ~ 1e-26
#define MBLK ((M_TOT + 255) / 256)  // kprep2 blocks
#define FILLB (CHUNKS * 8)          // 3328 fill-role blocks
#define K1B ((N_NODES + 63) / 64)   // 782 k1-role blocks
#define K1PAD 784                   // k1 role padded to multiple of 8 so the
                                    // fill role's f&7 -> XCD map stays bijective

typedef __attribute__((ext_vector_type(8))) short bf16x8;
typedef __attribute__((ext_vector_type(4))) float f32x4;

__device__ __forceinline__ unsigned short f2bf(float f) {
    unsigned int u = __float_as_uint(f);
    unsigned int r = (u + 0x7FFFu + ((u >> 16) & 1u)) >> 16;   // RNE
    return (unsigned short)r;
}
__device__ __forceinline__ float bf2f(unsigned short s) {
    return __uint_as_float(((unsigned int)s) << 16);
}

// ===========================================================================
// kprep2: coalesced per-edge meta  meta_by_m[m] = {ni|rel<<16, ew}
// + W f32->bf16 + cursor zeroing (memset dispatch folded in).
// ===========================================================================
__global__ __launch_bounds__(256) void kprep2(const int* __restrict__ node_in,
                                              const int* __restrict__ relation,
                                              const float* __restrict__ edge_weight,
                                              const float* __restrict__ W,
                                              int2* __restrict__ meta_by_m,
                                              unsigned short* __restrict__ Wb,
                                              int* __restrict__ cursor) {
    int m = blockIdx.x * 256 + threadIdx.x;
    if (m < NW / 4) {
        int i = m * 4;
        float4 v = *(const float4*)(W + i);
        ushort4 o; o.x = f2bf(v.x); o.y = f2bf(v.y); o.z = f2bf(v.z); o.w = f2bf(v.w);
        *(ushort4*)(Wb + i) = o;
    }
    if (m < N_NODES) cursor[m] = 0;               // replaces hipMemsetAsync
    if (m >= M_TOT) return;
    int ni, rl; float ew;
    if (m < N_EDGES) {
        ni = node_in[m]; rl = relation[m]; ew = edge_weight[m];
    } else {
        ni = m - N_EDGES; rl = RP1 - 1; ew = 1.0f;
    }
    int2 v; v.x = ni | (rl << 16); v.y = __float_as_int(ew);
    meta_by_m[m] = v;                               // coalesced full-line write
}

// ===========================================================================
// kbig (R18): merged fill + MFMA, long role first (R17). R18 delta: the k1
// role's xs[] LDS staging of x is DELETED -- each wave loads its own 16
// A-rows directly (4x16B per lane, exact traffic; x is L2/L3 resident).
// LDS_Block_Size drops 26624 -> 9216, so resident blocks/CU rise ~6 -> ~17,
// letting fill blocks actually co-reside with the k1 blocks (R17's counters:
// VALU 9% / Mfma 2% / HBM 29% = latency-bound with too little concurrency).
// ===========================================================================
__global__ __launch_bounds__(256) void kbig(const float* __restrict__ x,
                                            const unsigned short* __restrict__ Wb,
                                            unsigned short* __restrict__ hiddenb,
                                            const int* __restrict__ node_out,
                                            const int2* __restrict__ meta_by_m,
                                            int* __restrict__ cursor,
                                            int2* __restrict__ bucket) {
    const int t = threadIdx.x;

    if (blockIdx.x >= K1PAD) {
        // ---------------- fill role (coalesced meta, R15 body) ----------------
        const int f = blockIdx.x - K1PAD;
        const int r = f & 7;
        const int chunk = f >> 3;
        const int lo = r * RNG;
        const int hi = lo + RNG;
        int m = chunk * EPB + t;
#pragma unroll
        for (int it = 0; it < EPB / 256; it++, m += 256) {
            if (m < M_TOT) {
                int2 v = meta_by_m[m];              // coalesced (full chunk)
                int no = (m < N_EDGES) ? node_out[m] : (m - N_EDGES);
                if (no >= lo && no < hi) {
                    int pos = atomicAdd(&cursor[no], 1);
                    if (pos < BUCK) bucket[(size_t)no * BUCK + pos] = v;
                }
            }
        }
        return;
    }

    // ---------------- k1 (MFMA) role ----------------
    const int bx = blockIdx.x;
    if (bx >= K1B) return;                          // pad blocks
    __shared__ unsigned short st[4 * 16 * 72];      // 9216 B (only LDS now)
    const int wv = t >> 6, lane = t & 63;
    const int quad = lane >> 4, l16 = lane & 15;
    const int base = bx * 64 + wv * 16;

    // direct per-lane A-fragment load: row = base+l16, cols quad*8 and +32.
    // Clamped rows produce garbage only in their own (store-guarded) C row.
    int arow = base + l16;
    if (arow >= N_NODES) arow = N_NODES - 1;
    const float* xr = x + (size_t)arow * 64 + quad * 8;
    const float4 f0 = *(const float4*)(xr + 0);
    const float4 f1 = *(const float4*)(xr + 4);
    const float4 f2 = *(const float4*)(xr + 32);
    const float4 f3 = *(const float4*)(xr + 36);
    bf16x8 a0, a1;
    a0[0] = (short)f2bf(f0.x); a0[1] = (short)f2bf(f0.y);
    a0[2] = (short)f2bf(f0.z); a0[3] = (short)f2bf(f0.w);
    a0[4] = (short)f2bf(f1.x); a0[5] = (short)f2bf(f1.y);
    a0[6] = (short)f2bf(f1.z); a0[7] = (short)f2bf(f1.w);
    a1[0] = (short)f2bf(f2.x); a1[1] = (short)f2bf(f2.y);
    a1[2] = (short)f2bf(f2.z); a1[3] = (short)f2bf(f2.w);
    a1[4] = (short)f2bf(f3.x); a1[5] = (short)f2bf(f3.y);
    a1[6] = (short)f2bf(f3.z); a1[7] = (short)f2bf(f3.w);

    unsigned short* sw = &st[wv * 16 * 72];

    for (int r = 0; r < RP1; r++) {
        const unsigned short* Wr = Wb + r * 4096;
        f32x4 acc[4];
#pragma unroll
        for (int dt = 0; dt < 4; dt++) {
            const bf16x8 b0 = *(const bf16x8*)(Wr + (dt * 16 + l16) * 64 + quad * 8);
            const bf16x8 b1 = *(const bf16x8*)(Wr + (dt * 16 + l16) * 64 + quad * 8 + 32);
            f32x4 c = {0.f, 0.f, 0.f, 0.f};
            c = __builtin_amdgcn_mfma_f32_16x16x32_bf16(a0, b0, c, 0, 0, 0);
            c = __builtin_amdgcn_mfma_f32_16x16x32_bf16(a1, b1, c, 0, 0, 0);
            acc[dt] = c;
        }
#pragma unroll
        for (int dt = 0; dt < 4; dt++) {
#pragma unroll
            for (int v = 0; v < 4; v++) {
                sw[(quad * 4 + v) * 72 + dt * 16 + l16] = f2bf(acc[dt][v]);
            }
        }
        __threadfence_block();
#pragma unroll
        for (int q = 0; q < 2; q++) {
            int cid = q * 64 + lane;
            int row = cid >> 3;
            int ch = cid & 7;
            int n = base + row;
            if (n < N_NODES) {
                bf16x8 v = *(const bf16x8*)(sw + row * 72 + ch * 8);
                *(bf16x8*)(hiddenb + ((size_t)r * N_NODES + n) * 64 + ch * 8) = v;
            }
        }
        __threadfence_block();
    }
}

// ===========================================================================
// K3 (R18): dependent-round collapse. First-chunk bucket loads are issued
// UNCONDITIONALLY at n*BUCK+slot (no dependence on deg) together with deg and
// the prologue own-node gathers, all ahead of the q-staging barrier. The LDS
// meta[][] round-trip is replaced by __shfl from the loading lane; slots
// >= deg are sanitized (ni = own node, ew = 0) BEFORE the gather so stale
// bucket bytes can't form wild addresses. deg>32 tail (P ~ 1e-4/node) takes a
// cold direct-load path.
// ===========================================================================
__global__ __launch_bounds__(256) void k3_fused2(const unsigned short* __restrict__ hiddenb,
                                                 const float* __restrict__ query,
                                                 const int2* __restrict__ bucket,
                                                 const int* __restrict__ deg,
                                                 float* __restrict__ out) {
    __shared__ float qe[RP1 * 64];
    __shared__ float qo[RP1 * 64];
    __shared__ float bho[4][2][72];

    const int t = threadIdx.x;
    const int wv = t >> 6, lane = t & 63;
    const int pairi = blockIdx.x * 4 + wv;
    const int nA = pairi * 2, nB = nA + 1;
    const int e_lo = lane >> 3, h = lane & 7;

    // ---- issue all independent loads up front ----
    const int degAi = deg[nA], degBi = deg[nB];
    const int slot = lane & 31;
    const int nn = (lane >= 32) ? nB : nA;
    const int2 mt0 = bucket[(size_t)nn * BUCK + slot];   // always in-bounds

    const int prel = lane >> 3, ph = lane & 7;
    const bf16x8 ra = *(const bf16x8*)(hiddenb + ((size_t)(prel * N_NODES + nA)) * 64 + ph * 8);
    const bf16x8 rb = *(const bf16x8*)(hiddenb + ((size_t)(prel * N_NODES + nB)) * 64 + ph * 8);
    bf16x8 r8 = ra;
    if (lane < 16) {
        int n8 = (lane < 8) ? nA : nB;
        r8 = *(const bf16x8*)(hiddenb + ((size_t)(8 * N_NODES + n8)) * 64 + (lane & 7) * 8);
    }

    // ---- q staging (overlaps the loads above) ----
    for (int q = t; q < RP1 * 64; q += 256) {
        int j = q & 7, rh = q >> 3;
        qe[q] = query[rh * 16 + 2 * j];
        qo[q] = query[rh * 16 + 2 * j + 1];
    }
    __syncthreads();

    // ---- prologue: per-(node, rel, head) h_out . q_odd dots ----
    {
        const float* qop = &qo[(prel * 8 + ph) * 8];
        float da = 0.f, db = 0.f;
#pragma unroll
        for (int j = 0; j < 8; j++) {
            da += qop[j] * bf2f((unsigned short)ra[j]);
            db += qop[j] * bf2f((unsigned short)rb[j]);
        }
        bho[wv][0][prel * 8 + ph] = da;
        bho[wv][1][prel * 8 + ph] = db;
        if (lane < 16) {
            const float* q8p = &qo[(64 + (lane & 7)) * 8];
            float d8 = 0.f;
#pragma unroll
            for (int j = 0; j < 8; j++) d8 += q8p[j] * bf2f((unsigned short)r8[j]);
            bho[wv][(lane < 8) ? 0 : 1][64 + (lane & 7)] = d8;
        }
    }
    __threadfence_block();

    const int cA = min(32, degAi);
    const int cB = min(32, degBi);
    const int npA = (cA + 7) >> 3, npB = (cB + 7) >> 3;
    const float degA = (float)degAi, degB = (float)degBi;

    float accA[8] = {0.f, 0.f, 0.f, 0.f, 0.f, 0.f, 0.f, 0.f};
    float accB[8] = {0.f, 0.f, 0.f, 0.f, 0.f, 0.f, 0.f, 0.f};
    float spA = 0.f, spB = 0.f;

    // ---- chunk 0 (slots 0..31): shfl meta, batch gathers, then compute ----
    bf16x8 rA[4], rB[4];
    int relA[4], relB[4]; float ewA[4], ewB[4];
#pragma unroll
    for (int p = 0; p < 4; p++) {
        const int s = p * 8 + e_lo;
        if (p < npA) {
            int mx = __shfl(mt0.x, s);
            int my = __shfl(mt0.y, s);
            if (s >= cA) { mx = nA | ((RP1 - 1) << 16); my = 0; }
            int ni = mx & 0xffff, rl = mx >> 16;
            relA[p] = rl; ewA[p] = __int_as_float(my);
            rA[p] = *(const bf16x8*)(hiddenb + ((size_t)(rl * N_NODES + ni)) * 64 + h * 8);
        }
        if (p < npB) {
            int mx = __shfl(mt0.x, 32 + s);
            int my = __shfl(mt0.y, 32 + s);
            if (s >= cB) { mx = nB | ((RP1 - 1) << 16); my = 0; }
            int ni = mx & 0xffff, rl = mx >> 16;
            relB[p] = rl; ewB[p] = __int_as_float(my);
            rB[p] = *(const bf16x8*)(hiddenb + ((size_t)(rl * N_NODES + ni)) * 64 + h * 8);
        }
    }

#pragma unroll
    for (int p = 0; p < 4; p++) {
        if (p < npA) {
            const float* qp = &qe[(relA[p] * 8 + h) * 8];
            float hif[8];
#pragma unroll
            for (int j = 0; j < 8; j++) hif[j] = bf2f((unsigned short)rA[p][j]);
            float wp = bho[wv][0][relA[p] * 8 + h];
#pragma unroll
            for (int j = 0; j < 8; j++) wp += qp[j] * hif[j];
            wp = (wp > 0.f) ? wp : NEG_SLOPE * wp;
            float pa = __expf(wp) * ewA[p];
#pragma unroll
            for (int j = 0; j < 8; j++) accA[j] += pa * hif[j];
            spA += pa;
        }
        if (p < npB) {
            const float* qp = &qe[(relB[p] * 8 + h) * 8];
            float hif[8];
#pragma unroll
            for (int j = 0; j < 8; j++) hif[j] = bf2f((unsigned short)rB[p][j]);
            float wp = bho[wv][1][relB[p] * 8 + h];
#pragma unroll
            for (int j = 0; j < 8; j++) wp += qp[j] * hif[j];
            wp = (wp > 0.f) ? wp : NEG_SLOPE * wp;
            float pa = __expf(wp) * ewB[p];
#pragma unroll
            for (int j = 0; j < 8; j++) accB[j] += pa * hif[j];
            spB += pa;
        }
    }

    // ---- cold tail: slots 32..47 (P(deg > 32) ~ 1e-4 per node) ----
    if (degAi > 32 || degBi > 32) {
        const int capA = min(degAi, BUCK), capB = min(degBi, BUCK);
#pragma unroll
        for (int p = 0; p < 2; p++) {
            const int s = 32 + p * 8 + e_lo;
            if (s < capA) {
                int2 m2 = bucket[(size_t)nA * BUCK + s];
                int ni = m2.x & 0xffff, rl = m2.x >> 16;
                float ew = __int_as_float(m2.y);
                bf16x8 r = *(const bf16x8*)(hiddenb + ((size_t)(rl * N_NODES + ni)) * 64 + h * 8);
                const float* qp = &qe[(rl * 8 + h) * 8];
                float hif[8];
#pragma unroll
                for (int j = 0; j < 8; j++) hif[j] = bf2f((unsigned short)r[j]);
                float wp = bho[wv][0][rl * 8 + h];
#pragma unroll
                for (int j = 0; j < 8; j++) wp += qp[j] * hif[j];
                wp = (wp > 0.f) ? wp : NEG_SLOPE * wp;
                float pa = __expf(wp) * ew;
#pragma unroll
                for (int j = 0; j < 8; j++) accA[j] += pa * hif[j];
                spA += pa;
            }
            if (s < capB) {
                int2 m2 = bucket[(size_t)nB * BUCK + s];
                int ni = m2.x & 0xffff, rl = m2.x >> 16;
                float ew = __int_as_float(m2.y);
                bf16x8 r = *(const bf16x8*)(hiddenb + ((size_t)(rl * N_NODES + ni)) * 64 + h * 8);
                const float* qp = &qe[(rl * 8 + h) * 8];
                float hif[8];
#pragma unroll
                for (int j = 0; j < 8; j++) hif[j] = bf2f((unsigned short)r[j]);
                float wp = bho[wv][1][rl * 8 + h];
#pragma unroll
                for (int j = 0; j < 8; j++) wp += qp[j] * hif[j];
                wp = (wp > 0.f) ? wp : NEG_SLOPE * wp;
                float pa = __expf(wp) * ew;
#pragma unroll
                for (int j = 0; j < 8; j++) accB[j] += pa * hif[j];
                spB += pa;
            }
        }
    }

#pragma unroll
    for (int j = 0; j < 8; j++) {
        accA[j] += __shfl_xor(accA[j], 8);
        accA[j] += __shfl_xor(accA[j], 16);
        accA[j] += __shfl_xor(accA[j], 32);
        accB[j] += __shfl_xor(accB[j], 8);
        accB[j] += __shfl_xor(accB[j], 16);
        accB[j] += __shfl_xor(accB[j], 32);
    }
    spA += __shfl_xor(spA, 8); spA += __shfl_xor(spA, 16); spA += __shfl_xor(spA, 32);
    spB += __shfl_xor(spB, 8); spB += __shfl_xor(spB, 16); spB += __shfl_xor(spB, 32);

    if (lane < 8) {
        const float s = 1.f / ((spA / degA + EPS_F) * degA);
        float4 o0, o1;
        o0.x = fmaxf(accA[0] * s, 0.f); o0.y = fmaxf(accA[1] * s, 0.f);
        o0.z = fmaxf(accA[2] * s, 0.f); o0.w = fmaxf(accA[3] * s, 0.f);
        o1.x = fmaxf(accA[4] * s, 0.f); o1.y = fmaxf(accA[5] * s, 0.f);
        o1.z = fmaxf(accA[6] * s, 0.f); o1.w = fmaxf(accA[7] * s, 0.f);
        float* op = out + (size_t)nA * 64 + lane * 8;
        *(float4*)(op) = o0; *(float4*)(op + 4) = o1;
    } else if (lane < 16) {
        const float s = 1.f / ((spB / degB + EPS_F) * degB);
        float4 o0, o1;
        o0.x = fmaxf(accB[0] * s, 0.f); o0.y = fmaxf(accB[1] * s, 0.f);
        o0.z = fmaxf(accB[2] * s, 0.f); o0.w = fmaxf(accB[3] * s, 0.f);
        o1.x = fmaxf(accB[4] * s, 0.f); o1.y = fmaxf(accB[5] * s, 0.f);
        o1.z = fmaxf(accB[6] * s, 0.f); o1.w = fmaxf(accB[7] * s, 0.f);
        float* op = out + (size_t)nB * 64 + (lane - 8) * 8;
        *(float4*)(op) = o0; *(float4*)(op + 4) = o1;
    }
}

extern "C" void kernel_launch(void* const* d_in, const int* in_sizes, int n_in,
                              void* d_out, int out_size, void* d_ws, size_t ws_size,
                              hipStream_t stream) {
    const float* x        = (const float*)d_in[0];
    const float* W_tau    = (const float*)d_in[1];
    const float* query    = (const float*)d_in[2];
    const int*   node_in  = (const int*)d_in[3];
    const int*   node_out = (const int*)d_in[4];
    const int*   relation = (const int*)d_in[5];
    const float* edge_w   = (const float*)d_in[6];
    float* out = (float*)d_out;

    char* ws = (char*)d_ws;
    unsigned short* hiddenb   = (unsigned short*)(ws);                // 57,600,000
    unsigned short* Wb        = (unsigned short*)(ws + 57600000);     //     73,728
    int2*           meta_by_m = (int2*)(ws + 57673728);               //  6,800,000
    int2*           bucket    = (int2*)(ws + 64473728);               // 19,200,000
    int*            cursor    = (int*)(ws + 83673728);                //    200,000

    // per-edge meta + W conversion + cursor zeroing (coalesced streaming)
    kprep2<<<MBLK, 256, 0, stream>>>(node_in, relation, edge_w, W_tau,
                                     meta_by_m, Wb, cursor);

    // merged: MFMA transform (blocks 0..K1PAD, resident FIRST) overlapped
    // with bucket fill (blocks K1PAD..K1PAD+FILLB streaming in behind)
    kbig<<<K1PAD + FILLB, 256, 0, stream>>>(x, Wb, hiddenb, node_out, meta_by_m,
                                            cursor, bucket);

    // fused logits + aggregation + relu (2 nodes per wave)
    k3_fused2<<<(N_NODES / 2 + 3) / 4, 256, 0, stream>>>(hiddenb, query, bucket,
                                                         cursor, out);
}

// Round 5
// 168.092 us; speedup vs baseline: 1.2439x; 1.0069x over previous
//
#include <hip/hip_runtime.h>
#include <math.h>

#define N_NODES 50000
#define N_EDGES 800000
#define DOUT 64
#define NHEAD 8
#define RP1 9            // num_relations + 1 (self-loop relation id = 8)
#define NEG_SLOPE 0.2f
#define EPS_F 1e-10f
#define M_TOT (N_EDGES + N_NODES)   // 850000 edges incl. self-loops
#define NW (RP1 * DOUT * DOUT)      // 36,864 W elements

// --- two-level bucketing (R19/R20) ---
#define SUBSH 6                          // 64 nodes per subrange
#define NSUB ((N_NODES + 63) >> SUBSH)   // 782 subranges
#define SEGCAP 1536                      // slots per segment; lambda=1087, sigma=33
#define EPB 4096                         // edges per fill chunk
#define CHUNKS ((M_TOT + EPB - 1) / EPB) // 208 fill blocks
#define K1B ((N_NODES + 63) / 64)        // 782 k1-role blocks

typedef __attribute__((ext_vector_type(8))) short bf16x8;
typedef __attribute__((ext_vector_type(4))) float f32x4;

__device__ __forceinline__ unsigned short f2bf(float f) {
    unsigned int u = __float_as_uint(f);
    unsigned int r = (u + 0x7FFFu + ((u >> 16) & 1u)) >> 16;   // RNE
    return (unsigned short)r;
}
__device__ __forceinline__ float bf2f(unsigned short s) {
    return __uint_as_float(((unsigned int)s) << 16);
}

// ===========================================================================
// kprep2: W f32->bf16 + subcursor zeroing only (tiny).
// ===========================================================================
__global__ __launch_bounds__(256) void kprep2(const float* __restrict__ W,
                                              unsigned short* __restrict__ Wb,
                                              int* __restrict__ subcursor) {
    int m = blockIdx.x * 256 + threadIdx.x;
    if (m < NW / 4) {
        int i = m * 4;
        float4 v = *(const float4*)(W + i);
        ushort4 o; o.x = f2bf(v.x); o.y = f2bf(v.y); o.z = f2bf(v.z); o.w = f2bf(v.w);
        *(ushort4*)(Wb + i) = o;
    }
    if (m < NSUB) subcursor[m] = 0;
}

// ===========================================================================
// kbig (R20 = R19 resubmit): merged MFMA transform + two-level segment fill.
//   blocks [0, K1B)            : k1 MFMA role (resident first, R17 lesson)
//   blocks [K1B, K1B+CHUNKS)   : fill role, chunk = blockIdx - K1B
// Rationale (R18 post-mortem): fill was ATOMIC-THROUGHPUT-bound (R14: 850k
// device atomics ~= 45us regardless of locality). Two-level scheme: LDS count
// per 64-node subrange -> ONE global atomicAdd per non-empty (chunk,subrange)
// (~162k atomics, 5.2x fewer) -> scatter into reserved span. Per-node order
// recovered in k3 by an in-LDS counting sort.
// Packing: seg.x = ni | rel<<16 | (no&63)<<20.
// ===========================================================================
__global__ __launch_bounds__(256) void kbig(const float* __restrict__ x,
                                            const unsigned short* __restrict__ Wb,
                                            unsigned short* __restrict__ hiddenb,
                                            const int* __restrict__ node_in,
                                            const int* __restrict__ node_out,
                                            const int* __restrict__ relation,
                                            const float* __restrict__ edge_w,
                                            int* __restrict__ subcursor,
                                            int2* __restrict__ seg) {
    __shared__ union SM {
        unsigned short st[4 * 16 * 72];               // k1 role: 9216 B
        struct { int cnt[NSUB]; int base[NSUB]; } f;  // fill role: 6256 B
    } sm;
    const int t = threadIdx.x;

    if (blockIdx.x >= K1B) {
        // ---------------- fill role ----------------
        const int chunk = blockIdx.x - K1B;
        const int m0 = chunk * EPB;
        for (int s2 = t; s2 < NSUB; s2 += 256) sm.f.cnt[s2] = 0;
        __syncthreads();
        // pass 1: per-subrange count (LDS atomics, coalesced node_out read)
#pragma unroll
        for (int it = 0; it < EPB / 256; it++) {
            int m = m0 + it * 256 + t;
            if (m < M_TOT) {
                int no = (m < N_EDGES) ? node_out[m] : (m - N_EDGES);
                atomicAdd(&sm.f.cnt[no >> SUBSH], 1);
            }
        }
        __syncthreads();
        // reserve spans: one global atomic per non-empty subrange
        for (int s2 = t; s2 < NSUB; s2 += 256) {
            int c = sm.f.cnt[s2];
            sm.f.base[s2] = (c > 0) ? atomicAdd(&subcursor[s2], c) : 0;
        }
        __syncthreads();
        for (int s2 = t; s2 < NSUB; s2 += 256) sm.f.cnt[s2] = 0;
        __syncthreads();
        // pass 2: scatter into spans (edge arrays L2-hot from pass 1)
#pragma unroll
        for (int it = 0; it < EPB / 256; it++) {
            int m = m0 + it * 256 + t;
            if (m < M_TOT) {
                int no, ni, rl; float ew;
                if (m < N_EDGES) {
                    no = node_out[m]; ni = node_in[m];
                    rl = relation[m]; ew = edge_w[m];
                } else {
                    no = m - N_EDGES; ni = no; rl = RP1 - 1; ew = 1.0f;
                }
                int s2 = no >> SUBSH;
                int r = atomicAdd(&sm.f.cnt[s2], 1);
                int pos = sm.f.base[s2] + r;
                if (pos < SEGCAP) {
                    int2 v;
                    v.x = ni | (rl << 16) | ((no & 63) << 20);
                    v.y = __float_as_int(ew);
                    seg[(size_t)s2 * SEGCAP + pos] = v;
                }
            }
        }
        return;
    }

    // ---------------- k1 (MFMA) role (R18 body) ----------------
    const int bx = blockIdx.x;
    const int wv = t >> 6, lane = t & 63;
    const int quad = lane >> 4, l16 = lane & 15;
    const int base = bx * 64 + wv * 16;

    int arow = base + l16;
    if (arow >= N_NODES) arow = N_NODES - 1;
    const float* xr = x + (size_t)arow * 64 + quad * 8;
    const float4 f0 = *(const float4*)(xr + 0);
    const float4 f1 = *(const float4*)(xr + 4);
    const float4 f2 = *(const float4*)(xr + 32);
    const float4 f3 = *(const float4*)(xr + 36);
    bf16x8 a0, a1;
    a0[0] = (short)f2bf(f0.x); a0[1] = (short)f2bf(f0.y);
    a0[2] = (short)f2bf(f0.z); a0[3] = (short)f2bf(f0.w);
    a0[4] = (short)f2bf(f1.x); a0[5] = (short)f2bf(f1.y);
    a0[6] = (short)f2bf(f1.z); a0[7] = (short)f2bf(f1.w);
    a1[0] = (short)f2bf(f2.x); a1[1] = (short)f2bf(f2.y);
    a1[2] = (short)f2bf(f2.z); a1[3] = (short)f2bf(f2.w);
    a1[4] = (short)f2bf(f3.x); a1[5] = (short)f2bf(f3.y);
    a1[6] = (short)f2bf(f3.z); a1[7] = (short)f2bf(f3.w);

    unsigned short* sw = &sm.st[wv * 16 * 72];

    for (int r = 0; r < RP1; r++) {
        const unsigned short* Wr = Wb + r * 4096;
        f32x4 acc[4];
#pragma unroll
        for (int dt = 0; dt < 4; dt++) {
            const bf16x8 b0 = *(const bf16x8*)(Wr + (dt * 16 + l16) * 64 + quad * 8);
            const bf16x8 b1 = *(const bf16x8*)(Wr + (dt * 16 + l16) * 64 + quad * 8 + 32);
            f32x4 c = {0.f, 0.f, 0.f, 0.f};
            c = __builtin_amdgcn_mfma_f32_16x16x32_bf16(a0, b0, c, 0, 0, 0);
            c = __builtin_amdgcn_mfma_f32_16x16x32_bf16(a1, b1, c, 0, 0, 0);
            acc[dt] = c;
        }
#pragma unroll
        for (int dt = 0; dt < 4; dt++) {
#pragma unroll
            for (int v = 0; v < 4; v++) {
                sw[(quad * 4 + v) * 72 + dt * 16 + l16] = f2bf(acc[dt][v]);
            }
        }
        __threadfence_block();
#pragma unroll
        for (int q = 0; q < 2; q++) {
            int cid = q * 64 + lane;
            int row = cid >> 3;
            int ch = cid & 7;
            int n = base + row;
            if (n < N_NODES) {
                bf16x8 v = *(const bf16x8*)(sw + row * 72 + ch * 8);
                *(bf16x8*)(hiddenb + ((size_t)r * N_NODES + n) * 64 + ch * 8) = v;
            }
        }
        __threadfence_block();
    }
}

// ===========================================================================
// k3_seg (R20): one block per 64-node subrange. Segment -> LDS, in-LDS
// counting sort by node recovers per-node lists + degrees. Each wave runs the
// proven 2-node pipeline over 8 sequential pairs, meta from LDS. R20 delta vs
// R19: rl clamped to RP1-1 on unpack so even corrupted seg data cannot form
// an address outside the mapped hiddenb (defensive; closes the only
// theoretical page-fault path found in the R19 audit).
// ===========================================================================
__global__ __launch_bounds__(256) void k3_seg(const unsigned short* __restrict__ hiddenb,
                                              const float* __restrict__ query,
                                              const int2* __restrict__ seg,
                                              const int* __restrict__ subcursor,
                                              float* __restrict__ out) {
    __shared__ float qe[RP1 * 64];          // 2304 B
    __shared__ float qo[RP1 * 64];          // 2304 B
    __shared__ int2  smeta[SEGCAP];         // 12288 B
    __shared__ unsigned short sidx[SEGCAP]; // 3072 B
    __shared__ int cnt[64], start[64], cnt2[64];
    __shared__ float bho[4][2][72];         // 2304 B

    const int t = threadIdx.x;
    const int s = blockIdx.x;
    const int scnt = min(subcursor[s], SEGCAP);

    for (int q = t; q < RP1 * 64; q += 256) {
        int j = q & 7, rh = q >> 3;
        qe[q] = query[rh * 16 + 2 * j];
        qo[q] = query[rh * 16 + 2 * j + 1];
    }
    if (t < 64) { cnt[t] = 0; cnt2[t] = 0; }
    for (int i = t; i < scnt; i += 256) smeta[i] = seg[(size_t)s * SEGCAP + i];
    __syncthreads();

    for (int i = t; i < scnt; i += 256)
        atomicAdd(&cnt[(smeta[i].x >> 20) & 63], 1);
    __syncthreads();

    if (t < 64) {                       // wave 0: exclusive prefix scan of cnt
        int v = cnt[t];
        int sc = v;
#pragma unroll
        for (int d = 1; d < 64; d <<= 1) {
            int o = __shfl_up(sc, d);
            if (t >= d) sc += o;
        }
        start[t] = sc - v;
    }
    __syncthreads();

    for (int i = t; i < scnt; i += 256) {
        int nol = (smeta[i].x >> 20) & 63;
        int r = atomicAdd(&cnt2[nol], 1);
        sidx[start[nol] + r] = (unsigned short)i;
    }
    __syncthreads();

    const int wv = t >> 6, lane = t & 63;
    const int e_lo = lane >> 3, h = lane & 7;
    const int prel = lane >> 3, ph = lane & 7;

    for (int k = 0; k < 8; k++) {
        const int nAl = (k * 4 + wv) * 2, nBl = nAl + 1;
        const int nA = (s << SUBSH) + nAl, nB = nA + 1;
        if (nA >= N_NODES) continue;            // wave-uniform (last subrange)

        // ---- per-pair prologue: h_out . q_odd for all 9 rels ----
        {
            const bf16x8 ra = *(const bf16x8*)(hiddenb + ((size_t)(prel * N_NODES + nA)) * 64 + ph * 8);
            const bf16x8 rb = *(const bf16x8*)(hiddenb + ((size_t)(prel * N_NODES + nB)) * 64 + ph * 8);
            bf16x8 r8 = ra;
            if (lane < 16) {
                int n8 = (lane < 8) ? nA : nB;
                r8 = *(const bf16x8*)(hiddenb + ((size_t)(8 * N_NODES + n8)) * 64 + (lane & 7) * 8);
            }
            const float* qop = &qo[(prel * 8 + ph) * 8];
            float da = 0.f, db = 0.f;
#pragma unroll
            for (int j = 0; j < 8; j++) {
                da += qop[j] * bf2f((unsigned short)ra[j]);
                db += qop[j] * bf2f((unsigned short)rb[j]);
            }
            bho[wv][0][prel * 8 + ph] = da;
            bho[wv][1][prel * 8 + ph] = db;
            if (lane < 16) {
                const float* q8p = &qo[(64 + (lane & 7)) * 8];
                float d8 = 0.f;
#pragma unroll
                for (int j = 0; j < 8; j++) d8 += q8p[j] * bf2f((unsigned short)r8[j]);
                bho[wv][(lane < 8) ? 0 : 1][64 + (lane & 7)] = d8;
            }
        }
        __threadfence_block();

        const int cA = cnt[nAl], cB = cnt[nBl];
        const int stA = start[nAl], stB = start[nBl];
        const float degA = (float)cA, degB = (float)cB;
        const int cM = (cA > cB) ? cA : cB;

        float accA[8] = {0.f, 0.f, 0.f, 0.f, 0.f, 0.f, 0.f, 0.f};
        float accB[8] = {0.f, 0.f, 0.f, 0.f, 0.f, 0.f, 0.f, 0.f};
        float spA = 0.f, spB = 0.f;

        for (int j0 = 0; j0 < cM; j0 += 32) {
            bf16x8 rA[4], rB[4];
            int relA[4], relB[4]; float ewA[4], ewB[4];
#pragma unroll
            for (int p = 0; p < 4; p++) {
                const int sa = j0 + p * 8 + e_lo;
                if (sa < cA) {
                    int2 mv = smeta[sidx[stA + sa]];
                    int ni = mv.x & 0xffff;
                    int rl = min((mv.x >> 16) & 15, RP1 - 1);   // defensive clamp
                    relA[p] = rl; ewA[p] = __int_as_float(mv.y);
                    rA[p] = *(const bf16x8*)(hiddenb + ((size_t)(rl * N_NODES + ni)) * 64 + h * 8);
                }
                if (sa < cB) {
                    int2 mv = smeta[sidx[stB + sa]];
                    int ni = mv.x & 0xffff;
                    int rl = min((mv.x >> 16) & 15, RP1 - 1);   // defensive clamp
                    relB[p] = rl; ewB[p] = __int_as_float(mv.y);
                    rB[p] = *(const bf16x8*)(hiddenb + ((size_t)(rl * N_NODES + ni)) * 64 + h * 8);
                }
            }
#pragma unroll
            for (int p = 0; p < 4; p++) {
                const int sa = j0 + p * 8 + e_lo;
                if (sa < cA) {
                    const float* qp = &qe[(relA[p] * 8 + h) * 8];
                    float hif[8];
#pragma unroll
                    for (int j = 0; j < 8; j++) hif[j] = bf2f((unsigned short)rA[p][j]);
                    float wp = bho[wv][0][relA[p] * 8 + h];
#pragma unroll
                    for (int j = 0; j < 8; j++) wp += qp[j] * hif[j];
                    wp = (wp > 0.f) ? wp : NEG_SLOPE * wp;
                    float pa = __expf(wp) * ewA[p];
#pragma unroll
                    for (int j = 0; j < 8; j++) accA[j] += pa * hif[j];
                    spA += pa;
                }
                if (sa < cB) {
                    const float* qp = &qe[(relB[p] * 8 + h) * 8];
                    float hif[8];
#pragma unroll
                    for (int j = 0; j < 8; j++) hif[j] = bf2f((unsigned short)rB[p][j]);
                    float wp = bho[wv][1][relB[p] * 8 + h];
#pragma unroll
                    for (int j = 0; j < 8; j++) wp += qp[j] * hif[j];
                    wp = (wp > 0.f) ? wp : NEG_SLOPE * wp;
                    float pa = __expf(wp) * ewB[p];
#pragma unroll
                    for (int j = 0; j < 8; j++) accB[j] += pa * hif[j];
                    spB += pa;
                }
            }
        }

#pragma unroll
        for (int j = 0; j < 8; j++) {
            accA[j] += __shfl_xor(accA[j], 8);
            accA[j] += __shfl_xor(accA[j], 16);
            accA[j] += __shfl_xor(accA[j], 32);
            accB[j] += __shfl_xor(accB[j], 8);
            accB[j] += __shfl_xor(accB[j], 16);
            accB[j] += __shfl_xor(accB[j], 32);
        }
        spA += __shfl_xor(spA, 8); spA += __shfl_xor(spA, 16); spA += __shfl_xor(spA, 32);
        spB += __shfl_xor(spB, 8); spB += __shfl_xor(spB, 16); spB += __shfl_xor(spB, 32);

        if (lane < 8) {
            const float sc = 1.f / ((spA / degA + EPS_F) * degA);
            float4 o0, o1;
            o0.x = fmaxf(accA[0] * sc, 0.f); o0.y = fmaxf(accA[1] * sc, 0.f);
            o0.z = fmaxf(accA[2] * sc, 0.f); o0.w = fmaxf(accA[3] * sc, 0.f);
            o1.x = fmaxf(accA[4] * sc, 0.f); o1.y = fmaxf(accA[5] * sc, 0.f);
            o1.z = fmaxf(accA[6] * sc, 0.f); o1.w = fmaxf(accA[7] * sc, 0.f);
            float* op = out + (size_t)nA * 64 + lane * 8;
            *(float4*)(op) = o0; *(float4*)(op + 4) = o1;
        } else if (lane < 16) {
            const float sc = 1.f / ((spB / degB + EPS_F) * degB);
            float4 o0, o1;
            o0.x = fmaxf(accB[0] * sc, 0.f); o0.y = fmaxf(accB[1] * sc, 0.f);
            o0.z = fmaxf(accB[2] * sc, 0.f); o0.w = fmaxf(accB[3] * sc, 0.f);
            o1.x = fmaxf(accB[4] * sc, 0.f); o1.y = fmaxf(accB[5] * sc, 0.f);
            o1.z = fmaxf(accB[6] * sc, 0.f); o1.w = fmaxf(accB[7] * sc, 0.f);
            float* op = out + (size_t)nB * 64 + (lane - 8) * 8;
            *(float4*)(op) = o0; *(float4*)(op + 4) = o1;
        }
    }
}

extern "C" void kernel_launch(void* const* d_in, const int* in_sizes, int n_in,
                              void* d_out, int out_size, void* d_ws, size_t ws_size,
                              hipStream_t stream) {
    const float* x        = (const float*)d_in[0];
    const float* W_tau    = (const float*)d_in[1];
    const float* query    = (const float*)d_in[2];
    const int*   node_in  = (const int*)d_in[3];
    const int*   node_out = (const int*)d_in[4];
    const int*   relation = (const int*)d_in[5];
    const float* edge_w   = (const float*)d_in[6];
    float* out = (float*)d_out;

    char* ws = (char*)d_ws;
    unsigned short* hiddenb   = (unsigned short*)(ws);                // 57,600,000
    unsigned short* Wb        = (unsigned short*)(ws + 57600000);     //     73,728
    int2*           seg       = (int2*)(ws + 57673728);               //  9,609,216
    int*            subcursor = (int*)(ws + 67282944);                //      3,128

    // W conversion + subcursor zeroing (tiny)
    kprep2<<<(NW / 4 + 255) / 256, 256, 0, stream>>>(W_tau, Wb, subcursor);

    // merged: MFMA transform (blocks 0..K1B, resident first) overlapped with
    // two-level segment fill (blocks K1B..K1B+CHUNKS)
    kbig<<<K1B + CHUNKS, 256, 0, stream>>>(x, Wb, hiddenb, node_in, node_out,
                                           relation, edge_w, subcursor, seg);

    // per-subrange: LDS counting sort + fused logits/aggregation/relu
    k3_seg<<<NSUB, 256, 0, stream>>>(hiddenb, query, seg, subcursor, out);
}